// Round 10
// baseline (339.577 us; speedup 1.0000x reference)
//
#include <hip/hip_runtime.h>
#include <math.h>

#define NDET 16
#define NDIM 16

// ---- quad (4-lane) DPP broadcast: pure VALU, no LDS path -----------------
template<int OWNER>
__device__ __forceinline__ float bcast4f(float v) {
    constexpr int ctrl = OWNER * 0x55;  // quad_perm:[OWNER]*4
    return __int_as_float(
        __builtin_amdgcn_mov_dpp(__float_as_int(v), ctrl, 0xF, 0xF, true));
}

// ---- Householder QR step, COLUMN-INVOLUTION ORDER -------------------------
// Step K eliminates global column perm(K) = ((K&3)<<2)|(K>>2): an involution
// with 6 transpositions -> det(P) = +1 (no sign correction needed).
// Blocked ownership (lane l owns global columns 4l..4l+3 as c[j][.]), so:
//   owner lane  = K & 3   (cycles 0,1,2,3,...)
//   local index = K >> 2
//   fully-retired local columns (ALL lanes): j < K>>2  -> uniform j_min = K>>2
// The shrinking j-loop deletes ~17% of all FMAs with zero divergence.
template<int K>
__device__ __forceinline__ void qr_step(float (&c)[4][16], float &prod, float &sgn) {
    constexpr int OWNER = K & 3;    // lane owning column perm(K)
    constexpr int LC    = K >> 2;   // its local column index
    constexpr int JMIN  = K >> 2;   // first possibly-active local column

    // sum of squares over active rows K..15 (only owner's result is used)
    float s0 = 0.0f, s1 = 0.0f;
    #pragma unroll
    for (int i = K; i < 16; i += 2)     s0 = fmaf(c[LC][i], c[LC][i], s0);
    #pragma unroll
    for (int i = K + 1; i < 16; i += 2) s1 = fmaf(c[LC][i], c[LC][i], s1);

    const float n2    = bcast4f<OWNER>(s0 + s1);
    const float xK    = bcast4f<OWNER>(c[LC][K]);
    const float alpha = __builtin_amdgcn_sqrtf(n2);          // ||x|| > 0 a.s.
    const float vK    = xK + copysignf(alpha, xK);           // |vK| = alpha + |xK|
    const float beta  = __builtin_amdgcn_rcpf(alpha * fabsf(vK));
    prod *= alpha;
    sgn = (xK < 0.0f) ? -sgn : sgn;

    // broadcast reflector v (rows K..15) to all lanes of the quad
    float bv[16];                       // const-indexed -> registers
    bv[K] = vK;
    #pragma unroll
    for (int i = K + 1; i < 16; ++i) bv[i] = bcast4f<OWNER>(c[LC][i]);

    // apply H to local columns JMIN..3 (j < JMIN are retired on every lane)
    #pragma unroll
    for (int j = JMIN; j < 4; ++j) {
        float w0 = bv[K] * c[j][K], w1 = 0.0f;
        #pragma unroll
        for (int i = K + 1; i < 16; i += 2) w0 = fmaf(bv[i], c[j][i], w0);
        #pragma unroll
        for (int i = K + 2; i < 16; i += 2) w1 = fmaf(bv[i], c[j][i], w1);
        const float t = (w0 + w1) * beta;
        #pragma unroll
        for (int i = K; i < 16; ++i)
            c[j][i] = fmaf(-t, bv[i], c[j][i]);
    }
}

template<int K>
__device__ __forceinline__ void qr_all(float (&c)[4][16], float &prod, float &sgn) {
    qr_step<K>(c, prod, sgn);
    if constexpr (K < 14) qr_all<K + 1>(c, prod, sgn);
}

// 8 waves/EU requested: forces VGPR <= 64 so occupancy cap doesn't halve.
__global__ __launch_bounds__(256, 8) void logabssumdet_kernel(
    const float* __restrict__ a,
    const float* __restrict__ b,
    const float* __restrict__ w,
    float* __restrict__ out,
    int n_samples)
{
    const int tid    = threadIdx.x;
    const int lane4  = tid & 3;
    const int group  = tid >> 2;                    // 0..63 in block
    const int mat_id = blockIdx.x * 64 + group;     // = sample*16 + det
    const int n_mats = n_samples * NDET;

    __shared__ float sx[64];
    __shared__ float ss[64];

    float x = 0.0f, sgn = 1.0f;

    if (mat_id < n_mats) {
        #pragma unroll 1   // one QR body in I-cache (rolled m-loop: best so far)
        for (int m = 0; m < 2; ++m) {
            const float* src = (m == 0) ? a : b;
            const float4* mb =
                reinterpret_cast<const float4*>(src + (size_t)mat_id * (NDIM * NDIM)) + lane4;

            float c[4][16];
            #pragma unroll
            for (int i = 0; i < 16; ++i) {
                const float4 v = mb[i * 4];         // 64B contiguous per quad
                c[0][i] = v.x; c[1][i] = v.y; c[2][i] = v.z; c[3][i] = v.w;
            }

            float prod = 1.0f;                      // = prod of alpha_K (>0)
            qr_all<0>(c, prod, sgn);                // 15 reflections
            // remaining column perm(15)=15: lane 3, local 3, row 15
            prod *= bcast4f<3>(c[3][15]);

            // det = (prod of s_K, folded in sgn) * prod ; f32-range safe
            x += __logf(fabsf(prod));
            sgn = (prod < 0.0f) ? -sgn : sgn;
        }
    }

    if (lane4 == 0) { sx[group] = x; ss[group] = sgn; }
    __syncthreads();

    // 4 samples per block; one thread finishes each sample's 16-det LSE
    if (tid < 4) {
        const int sample = blockIdx.x * 4 + tid;
        if (sample < n_samples) {
            const int base = tid * NDET;
            float xmax = -INFINITY;
            #pragma unroll
            for (int d = 0; d < NDET; ++d) xmax = fmaxf(xmax, sx[base + d]);
            float sum = 0.0f;
            #pragma unroll
            for (int d = 0; d < NDET; ++d)
                sum += ss[base + d] * __expf(sx[base + d] - xmax) * w[d];
            out[sample] = __logf(fabsf(sum)) + xmax;
            out[n_samples + sample] = (sum > 0.0f) ? 1.0f : ((sum < 0.0f) ? -1.0f : 0.0f);
        }
    }
}

extern "C" void kernel_launch(void* const* d_in, const int* in_sizes, int n_in,
                              void* d_out, int out_size, void* d_ws, size_t ws_size,
                              hipStream_t stream)
{
    const float* a = (const float*)d_in[0];
    const float* b = (const float*)d_in[1];
    const float* w = (const float*)d_in[2];
    float* out = (float*)d_out;

    const int n_samples = in_sizes[0] / (NDET * NDIM * NDIM);
    const int blocks = (n_samples + 3) / 4;   // 4 samples (64 dets) per block
    logabssumdet_kernel<<<blocks, 256, 0, stream>>>(a, b, w, out, n_samples);
}

// Round 11
// 46.730 us; speedup vs baseline: 7.2668x; 7.2668x over previous
//
#include <hip/hip_runtime.h>
#include <math.h>

#define NDET 16
#define NDIM 16

// ---- quad (4-lane) DPP broadcast: pure VALU, no LDS path -----------------
template<int OWNER>
__device__ __forceinline__ float bcast4f(float v) {
    constexpr int ctrl = OWNER * 0x55;  // quad_perm:[OWNER]*4
    return __int_as_float(
        __builtin_amdgcn_mov_dpp(__float_as_int(v), ctrl, 0xF, 0xF, true));
}

// ---- Householder QR step, COLUMN-INVOLUTION ORDER -------------------------
// Step K eliminates global column perm(K) = ((K&3)<<2)|(K>>2): an involution
// with 6 transpositions -> det(P) = +1 (no sign correction needed).
// Blocked ownership (lane l owns global columns 4l..4l+3 as c[j][.]), so:
//   owner lane  = K & 3   (cycles 0,1,2,3,...)
//   local index = K >> 2
//   fully-retired local columns (ALL lanes): j < K>>2  -> uniform j_min = K>>2
// The shrinking j-loop deletes ~17% of all FMAs with zero divergence.
template<int K>
__device__ __forceinline__ void qr_step(float (&c)[4][16], float &prod, float &sgn) {
    constexpr int OWNER = K & 3;    // lane owning column perm(K)
    constexpr int LC    = K >> 2;   // its local column index
    constexpr int JMIN  = K >> 2;   // first possibly-active local column

    // sum of squares over active rows K..15 (only owner's result is used)
    float s0 = 0.0f, s1 = 0.0f;
    #pragma unroll
    for (int i = K; i < 16; i += 2)     s0 = fmaf(c[LC][i], c[LC][i], s0);
    #pragma unroll
    for (int i = K + 1; i < 16; i += 2) s1 = fmaf(c[LC][i], c[LC][i], s1);

    const float n2    = bcast4f<OWNER>(s0 + s1);
    const float xK    = bcast4f<OWNER>(c[LC][K]);
    const float alpha = __builtin_amdgcn_sqrtf(n2);          // ||x|| > 0 a.s.
    const float vK    = xK + copysignf(alpha, xK);           // |vK| = alpha + |xK|
    const float beta  = __builtin_amdgcn_rcpf(alpha * fabsf(vK));
    prod *= alpha;
    sgn = (xK < 0.0f) ? -sgn : sgn;

    // broadcast reflector v (rows K..15) to all lanes of the quad
    float bv[16];                       // const-indexed -> registers
    bv[K] = vK;
    #pragma unroll
    for (int i = K + 1; i < 16; ++i) bv[i] = bcast4f<OWNER>(c[LC][i]);

    // apply H to local columns JMIN..3 (j < JMIN are retired on every lane)
    #pragma unroll
    for (int j = JMIN; j < 4; ++j) {
        float w0 = bv[K] * c[j][K], w1 = 0.0f;
        #pragma unroll
        for (int i = K + 1; i < 16; i += 2) w0 = fmaf(bv[i], c[j][i], w0);
        #pragma unroll
        for (int i = K + 2; i < 16; i += 2) w1 = fmaf(bv[i], c[j][i], w1);
        const float t = (w0 + w1) * beta;
        #pragma unroll
        for (int i = K; i < 16; ++i)
            c[j][i] = fmaf(-t, bv[i], c[j][i]);
    }
}

template<int K>
__device__ __forceinline__ void qr_all(float (&c)[4][16], float &prod, float &sgn) {
    qr_step<K>(c, prod, sgn);
    if constexpr (K < 14) qr_all<K + 1>(c, prod, sgn);
}

// NOTE: no min-waves clause — R10's (256,8) forced VGPR 68->32 and spilled
// 1.4 GB of scratch traffic (WRITE_SIZE 810 MB), 50->340 us. Let the
// allocator pick; ~68 VGPR = 4 waves/SIMD is the right operating point.
__global__ __launch_bounds__(256) void logabssumdet_kernel(
    const float* __restrict__ a,
    const float* __restrict__ b,
    const float* __restrict__ w,
    float* __restrict__ out,
    int n_samples)
{
    const int tid    = threadIdx.x;
    const int lane4  = tid & 3;
    const int group  = tid >> 2;                    // 0..63 in block
    const int mat_id = blockIdx.x * 64 + group;     // = sample*16 + det
    const int n_mats = n_samples * NDET;

    __shared__ float sx[64];
    __shared__ float ss[64];

    float x = 0.0f, sgn = 1.0f;

    if (mat_id < n_mats) {
        #pragma unroll 1   // one QR body in I-cache (rolled m-loop: best so far)
        for (int m = 0; m < 2; ++m) {
            const float* src = (m == 0) ? a : b;
            const float4* mb =
                reinterpret_cast<const float4*>(src + (size_t)mat_id * (NDIM * NDIM)) + lane4;

            float c[4][16];
            #pragma unroll
            for (int i = 0; i < 16; ++i) {
                const float4 v = mb[i * 4];         // 64B contiguous per quad
                c[0][i] = v.x; c[1][i] = v.y; c[2][i] = v.z; c[3][i] = v.w;
            }

            float prod = 1.0f;                      // = prod of alpha_K (>0)
            qr_all<0>(c, prod, sgn);                // 15 reflections
            // remaining column perm(15)=15: lane 3, local 3, row 15
            prod *= bcast4f<3>(c[3][15]);

            // det = (prod of s_K, folded in sgn) * prod ; f32-range safe
            x += __logf(fabsf(prod));
            sgn = (prod < 0.0f) ? -sgn : sgn;
        }
    }

    if (lane4 == 0) { sx[group] = x; ss[group] = sgn; }
    __syncthreads();

    // 4 samples per block; one thread finishes each sample's 16-det LSE
    if (tid < 4) {
        const int sample = blockIdx.x * 4 + tid;
        if (sample < n_samples) {
            const int base = tid * NDET;
            float xmax = -INFINITY;
            #pragma unroll
            for (int d = 0; d < NDET; ++d) xmax = fmaxf(xmax, sx[base + d]);
            float sum = 0.0f;
            #pragma unroll
            for (int d = 0; d < NDET; ++d)
                sum += ss[base + d] * __expf(sx[base + d] - xmax) * w[d];
            out[sample] = __logf(fabsf(sum)) + xmax;
            out[n_samples + sample] = (sum > 0.0f) ? 1.0f : ((sum < 0.0f) ? -1.0f : 0.0f);
        }
    }
}

extern "C" void kernel_launch(void* const* d_in, const int* in_sizes, int n_in,
                              void* d_out, int out_size, void* d_ws, size_t ws_size,
                              hipStream_t stream)
{
    const float* a = (const float*)d_in[0];
    const float* b = (const float*)d_in[1];
    const float* w = (const float*)d_in[2];
    float* out = (float*)d_out;

    const int n_samples = in_sizes[0] / (NDET * NDIM * NDIM);
    const int blocks = (n_samples + 3) / 4;   // 4 samples (64 dets) per block
    logabssumdet_kernel<<<blocks, 256, 0, stream>>>(a, b, w, out, n_samples);
}